// Round 6
// baseline (439.695 us; speedup 1.0000x reference)
//
#include <hip/hip_runtime.h>
#include <hip/hip_bf16.h>

#define HW    12288
#define Wimg  192
#define Himg  64
#define Wpad  194
#define Ppad  12804   // 66*194

// ---------------------------------------------------------------------------
// K1: deformable gather.  grid = (192 px tiles, 8 channel blocks of 32).
// ---------------------------------------------------------------------------
__global__ __launch_bounds__(256) void k_deform(
    const float* __restrict__ x,     // 256 x HW
    const float* __restrict__ xr,    // HW
    const float* __restrict__ rout,  // 256 x 9
    float* __restrict__ y0)          // 256 x HW (fp32)
{
    __shared__ int   s_idx[36][64];  // [k*4+j][pixel]
    __shared__ float s_w[36][64];
    __shared__ float s_r[32][9];     // this block's 32 channels x 9 taps

    const int tile = blockIdx.x;     // 0..191
    const int cblk = blockIdx.y;     // 0..7
    const int tid  = threadIdx.x;
    const int px0  = tile * 64;

    for (int i = tid; i < 32 * 9; i += 256) {
        int cl = i / 9, k = i - cl * 9;
        s_r[cl][k] = rout[(cblk * 32 + cl) * 9 + k];
    }

    for (int item = tid; item < 64 * 9; item += 256) {
        int pl = item / 9, k = item - pl * 9;
        int gp = px0 + pl;
        int h = gp / Wimg, w = gp - h * Wimg;
        int xo = (k % 3) - 1;
        int yo = (k / 3) - 1;
        float off = 3.0f / (1.0f + expf(-xr[gp]));
        float ov  = off * (float)xo;
        int   iv  = yo * Wpad;
        int   pre = (h + 1) * Wpad + (w + 1) + xo + iv;
        float after = (float)(pre + iv) + ov;
        int fl = (int)floorf(ov);
        int ce = (int)ceilf(ov);
        int av_f  = min(max(pre + fl + iv, 0), Ppad - 1);
        int av_f1 = min(max(av_f + xo,    0), Ppad - 1);
        int av_c  = min(max(pre + ce + iv, 0), Ppad - 1);
        int av_c1 = min(max(av_c + xo,    0), Ppad - 1);
        float wf  = fabsf(after - (float)av_f);
        float wf1 = fabsf((float)av_f1 - after);
        float wc1 = fabsf(after - (float)av_c1);
        float wc  = fabsf((float)av_c - after);
        float s1 = wf  * (1.0f / Wpad);
        float s2 = wc1 * (1.0f / Wpad);
        int   idx4[4] = { av_f, av_f1, av_c1, av_c };
        float w4[4]   = { s1 * wf, s1 * wf1, s2 * wc1, s2 * wc };
        #pragma unroll
        for (int j = 0; j < 4; ++j) {
            int av = idx4[j];
            int r  = av / Wpad;
            int cc = av - r * Wpad;
            bool inb = (r >= 1) && (r <= Himg) && (cc >= 1) && (cc <= Wimg);
            s_idx[k * 4 + j][pl] = inb ? ((r - 1) * Wimg + (cc - 1)) : 0;
            s_w[k * 4 + j][pl]   = inb ? w4[j] : 0.0f;
        }
    }
    __syncthreads();

    const int pl    = tid & 63;
    const int clane = tid >> 6;
    const int gp    = px0 + pl;
    for (int i = 0; i < 8; ++i) {
        int cl = clane + 4 * i;          // local channel 0..31
        int c  = cblk * 32 + cl;
        const float* xc = x + (size_t)c * HW;
        float acc = 0.0f;
        #pragma unroll
        for (int k = 0; k < 9; ++k) {
            float part = 0.0f;
            #pragma unroll
            for (int j = 0; j < 4; ++j) {
                part += s_w[k * 4 + j][pl] * xc[s_idx[k * 4 + j][pl]];
            }
            acc += s_r[cl][k] * part;
        }
        y0[(size_t)c * HW + gp] = acc;
    }
}

// ---------------------------------------------------------------------------
// Pointwise GEMM:  Z[128 x HW] = W[128 x CIN] * A[CIN x HW], full K/block.
// Block = 64 px x 32 outs, grid (192, 4) = 768 blocks.  4 waves/block; each
// wave owns 8 outs so weight reads are wave-uniform -> SGPR s_loads (no VMEM,
// no LDS for W).  A staged in LDS in 64-deep chunks (16 KB, conflict-free).
// Plain coalesced stores; BN stats fused via per-wave reduce + tiny atomics.
// ---------------------------------------------------------------------------
template <int CIN>
__global__ __launch_bounds__(256) void k_pw(
    const float* __restrict__ A,     // CIN x HW
    const float* __restrict__ Wt,    // CIN x 128 (transposed weights)
    float* __restrict__ Z,           // 128 x HW
    float* __restrict__ psum)        // 128 x {sum,sumsq}, pre-zeroed
{
    __shared__ float s_a[64][64];
    const int tid  = threadIdx.x;
    const int lane = tid & 63;       // pixel lane
    const int wv   = __builtin_amdgcn_readfirstlane(tid >> 6);
    const int o0   = blockIdx.y * 32 + wv * 8;
    const int px0  = blockIdx.x * 64;

    float acc[8];
    #pragma unroll
    for (int i = 0; i < 8; ++i) acc[i] = 0.0f;

    const int sr = tid >> 6;         // staging row base, rows sr+4j
    const int sc = tid & 63;

    for (int cb = 0; cb < CIN; cb += 64) {
        #pragma unroll
        for (int j = 0; j < 16; ++j)
            s_a[sr + 4 * j][sc] = A[(size_t)(cb + sr + 4 * j) * HW + px0 + sc];
        __syncthreads();
        #pragma unroll 8
        for (int cc = 0; cc < 64; ++cc) {
            float a = s_a[cc][lane];
            const float* wrow = Wt + (size_t)(cb + cc) * 128 + o0;  // uniform
            #pragma unroll
            for (int i = 0; i < 8; ++i)
                acc[i] += a * wrow[i];
        }
        __syncthreads();
    }

    #pragma unroll
    for (int i = 0; i < 8; ++i)
        Z[(size_t)(o0 + i) * HW + px0 + lane] = acc[i];

    // fused BN partial stats: per-wave reduction over the 64 pixel lanes
    #pragma unroll
    for (int i = 0; i < 8; ++i) {
        float s = acc[i];
        float q = acc[i] * acc[i];
        #pragma unroll
        for (int off = 32; off > 0; off >>= 1) {
            s += __shfl_down(s, off, 64);
            q += __shfl_down(q, off, 64);
        }
        if (lane == 0) {
            atomicAdd(&psum[2 * (o0 + i)],     s);
            atomicAdd(&psum[2 * (o0 + i) + 1], q);
        }
    }
}

// ---------------------------------------------------------------------------
// Finalize BN params in place: (sum, sumsq) -> (scale, shift).  1 block.
// ---------------------------------------------------------------------------
__global__ void k_params(float* __restrict__ p,
                         const float* __restrict__ g,
                         const float* __restrict__ b)
{
    const int c = threadIdx.x;   // 128
    float s = p[2 * c], q = p[2 * c + 1];
    float mu  = s * (1.0f / HW);
    float var = q * (1.0f / HW) - mu * mu;
    float sc  = g[c] * rsqrtf(var + 1e-5f);
    p[2 * c]     = sc;
    p[2 * c + 1] = b[c] - mu * sc;
}

// ---------------------------------------------------------------------------
// Weight transpose: Wt[c][o] = W[o][c].  grid = 128.
// ---------------------------------------------------------------------------
__global__ void k_tr(const float* __restrict__ W, float* __restrict__ Wt, int Cin)
{
    const int o = blockIdx.x;
    for (int c = threadIdx.x; c < Cin; c += 256)
        Wt[(size_t)c * 128 + o] = W[o * Cin + c];
}

// ---------------------------------------------------------------------------
// Fused BN+LeakyReLU then depthwise 3x3 (pad 1).  One thread / output.
// ---------------------------------------------------------------------------
__global__ __launch_bounds__(256) void k_dw(
    const float* __restrict__ Z,
    const float* __restrict__ params,
    const float* __restrict__ dwgt,  // 128 x 9
    float* __restrict__ D)
{
    const int t = blockIdx.x * 256 + threadIdx.x;
    const int c = t / HW;
    const int p = t - c * HW;
    const int h = p / Wimg;
    const int w = p - h * Wimg;
    const float sc = params[2 * c];
    const float sh = params[2 * c + 1];
    float wk[9];
    #pragma unroll
    for (int k = 0; k < 9; ++k) wk[k] = dwgt[c * 9 + k];
    float acc = 0.0f;
    #pragma unroll
    for (int ky = 0; ky < 3; ++ky) {
        int hh = h + ky - 1;
        if (hh < 0 || hh >= Himg) continue;
        #pragma unroll
        for (int kx = 0; kx < 3; ++kx) {
            int ww = w + kx - 1;
            if (ww < 0 || ww >= Wimg) continue;
            float z = Z[(size_t)c * HW + hh * Wimg + ww];
            float y = z * sc + sh;
            y = (y >= 0.0f) ? y : 0.01f * y;
            acc += wk[ky * 3 + kx] * y;
        }
    }
    D[t] = acc;
}

// ---------------------------------------------------------------------------
// Final BN+LeakyReLU (fp32 out).
// ---------------------------------------------------------------------------
__global__ __launch_bounds__(256) void k_final(
    const float* __restrict__ Z,
    const float* __restrict__ params,
    float* __restrict__ out)
{
    const int t = blockIdx.x * 256 + threadIdx.x;
    const int c = t / HW;
    float v = Z[t] * params[2 * c] + params[2 * c + 1];
    v = (v >= 0.0f) ? v : 0.01f * v;
    out[t] = v;
}

// ---------------------------------------------------------------------------
extern "C" void kernel_launch(void* const* d_in, const int* in_sizes, int n_in,
                              void* d_out, int out_size, void* d_ws, size_t ws_size,
                              hipStream_t stream) {
    const float* x   = (const float*)d_in[0];
    const float* xr  = (const float*)d_in[1];
    const float* ro  = (const float*)d_in[2];
    const float* wr  = (const float*)d_in[3];
    const float* gr  = (const float*)d_in[4];
    const float* br  = (const float*)d_in[5];
    const float* dw1 = (const float*)d_in[6];
    const float* pw1 = (const float*)d_in[7];
    const float* g1  = (const float*)d_in[8];
    const float* b1  = (const float*)d_in[9];
    const float* dw2 = (const float*)d_in[10];
    const float* pw2 = (const float*)d_in[11];
    const float* g2  = (const float*)d_in[12];
    const float* b2  = (const float*)d_in[13];

    float* ws = (float*)d_ws;
    float* A  = ws;                  // 3,145,728 floats
    float* B  = ws + 3145728;        // 1,572,864
    float* C  = ws + 4718592;        // 1,572,864
    float* y0 = A;
    float* z1 = B;
    float* d1 = C;
    float* z2 = A;                   // first half of A
    float* d2 = B;
    float* z3 = A + 1572864;         // second half of A
    float* wrT  = C;                 // dead before d1 written
    float* pw1T = B;                 // staged after z1 dead
    float* pw2T = C;                 // staged after d1 dead
    float* p1 = ws + 6291456;
    float* p2 = p1 + 256;
    float* p3 = p2 + 256;
    float* out = (float*)d_out;

    hipMemsetAsync(p1, 0, 768 * 4, stream);            // p1,p2,p3
    k_tr<<<128, 256, 0, stream>>>(wr, wrT, 256);
    k_deform<<<dim3(192, 8), 256, 0, stream>>>(x, xr, ro, y0);
    k_pw<256><<<dim3(192, 4), 256, 0, stream>>>(y0, wrT, z1, p1);
    k_params<<<1, 128, 0, stream>>>(p1, gr, br);
    k_dw<<<6144, 256, 0, stream>>>(z1, p1, dw1, d1);
    k_tr<<<128, 256, 0, stream>>>(pw1, pw1T, 128);     // z1 (B) dead
    k_pw<128><<<dim3(192, 4), 256, 0, stream>>>(d1, pw1T, z2, p2);
    k_params<<<1, 128, 0, stream>>>(p2, g1, b1);
    k_dw<<<6144, 256, 0, stream>>>(z2, p2, dw2, d2);   // overwrites pw1T (dead)
    k_tr<<<128, 256, 0, stream>>>(pw2, pw2T, 128);     // d1 (C) dead
    k_pw<128><<<dim3(192, 4), 256, 0, stream>>>(d2, pw2T, z3, p3);
    k_params<<<1, 128, 0, stream>>>(p3, g2, b2);
    k_final<<<6144, 256, 0, stream>>>(z3, p3, out);
}

// Round 8
// 222.716 us; speedup vs baseline: 1.9742x; 1.9742x over previous
//
#include <hip/hip_runtime.h>
#include <hip/hip_bf16.h>

#define HW    12288
#define Wimg  192
#define Himg  64
#define Wpad  194
#define Ppad  12804   // 66*194

// ---------------------------------------------------------------------------
// K1: deformable gather.  grid = (192 px tiles, 8 channel blocks of 32).
// ---------------------------------------------------------------------------
__global__ __launch_bounds__(256) void k_deform(
    const float* __restrict__ x,     // 256 x HW
    const float* __restrict__ xr,    // HW
    const float* __restrict__ rout,  // 256 x 9
    float* __restrict__ y0)          // 256 x HW (fp32)
{
    __shared__ int   s_idx[36][64];  // [k*4+j][pixel]
    __shared__ float s_w[36][64];
    __shared__ float s_r[32][9];     // this block's 32 channels x 9 taps

    const int tile = blockIdx.x;     // 0..191
    const int cblk = blockIdx.y;     // 0..7
    const int tid  = threadIdx.x;
    const int px0  = tile * 64;

    for (int i = tid; i < 32 * 9; i += 256) {
        int cl = i / 9, k = i - cl * 9;
        s_r[cl][k] = rout[(cblk * 32 + cl) * 9 + k];
    }

    for (int item = tid; item < 64 * 9; item += 256) {
        int pl = item / 9, k = item - pl * 9;
        int gp = px0 + pl;
        int h = gp / Wimg, w = gp - h * Wimg;
        int xo = (k % 3) - 1;
        int yo = (k / 3) - 1;
        float off = 3.0f / (1.0f + expf(-xr[gp]));
        float ov  = off * (float)xo;
        int   iv  = yo * Wpad;
        int   pre = (h + 1) * Wpad + (w + 1) + xo + iv;
        float after = (float)(pre + iv) + ov;
        int fl = (int)floorf(ov);
        int ce = (int)ceilf(ov);
        int av_f  = min(max(pre + fl + iv, 0), Ppad - 1);
        int av_f1 = min(max(av_f + xo,    0), Ppad - 1);
        int av_c  = min(max(pre + ce + iv, 0), Ppad - 1);
        int av_c1 = min(max(av_c + xo,    0), Ppad - 1);
        float wf  = fabsf(after - (float)av_f);
        float wf1 = fabsf((float)av_f1 - after);
        float wc1 = fabsf(after - (float)av_c1);
        float wc  = fabsf((float)av_c - after);
        float s1 = wf  * (1.0f / Wpad);
        float s2 = wc1 * (1.0f / Wpad);
        int   idx4[4] = { av_f, av_f1, av_c1, av_c };
        float w4[4]   = { s1 * wf, s1 * wf1, s2 * wc1, s2 * wc };
        #pragma unroll
        for (int j = 0; j < 4; ++j) {
            int av = idx4[j];
            int r  = av / Wpad;
            int cc = av - r * Wpad;
            bool inb = (r >= 1) && (r <= Himg) && (cc >= 1) && (cc <= Wimg);
            s_idx[k * 4 + j][pl] = inb ? ((r - 1) * Wimg + (cc - 1)) : 0;
            s_w[k * 4 + j][pl]   = inb ? w4[j] : 0.0f;
        }
    }
    __syncthreads();

    const int pl    = tid & 63;
    const int clane = tid >> 6;
    const int gp    = px0 + pl;
    for (int i = 0; i < 8; ++i) {
        int cl = clane + 4 * i;          // local channel 0..31
        int c  = cblk * 32 + cl;
        const float* xc = x + (size_t)c * HW;
        float acc = 0.0f;
        #pragma unroll
        for (int k = 0; k < 9; ++k) {
            float part = 0.0f;
            #pragma unroll
            for (int j = 0; j < 4; ++j) {
                part += s_w[k * 4 + j][pl] * xc[s_idx[k * 4 + j][pl]];
            }
            acc += s_r[cl][k] * part;
        }
        y0[(size_t)c * HW + gp] = acc;
    }
}

// ---------------------------------------------------------------------------
// Pointwise GEMM, split-K into partial buffers (NO atomics):
//   Zp[z][128 x HW] = W[128, K-half z] * A[K-half z, HW]
// Block = 64 px x 64 outs, grid (192, 2, 2) = 768 blocks.  256 threads, 4x4
// register tile, 32-deep LDS chunks.  W staged directly from the original
// [128 x CIN] layout (transpose-in-LDS, +4 pad -> conflict-free, float4
// aligned).  Plain float4 stores.
// ---------------------------------------------------------------------------
template <int CIN>
__global__ __launch_bounds__(256) void k_pw(
    const float* __restrict__ A,     // CIN x HW
    const float* __restrict__ Wm,    // 128 x CIN (original layout)
    float* __restrict__ Zp0,         // partial for K-half 0
    float* __restrict__ Zp1)         // partial for K-half 1
{
    __shared__ float s_a[32][64];
    __shared__ float s_w[32][68];    // [c_local][o_local], +4 pad
    const int tid = threadIdx.x;
    const int tx  = tid & 15;        // px group (4 px)
    const int ty  = tid >> 4;        // o group (4 outs)
    const int px0 = blockIdx.x * 64;
    const int o0  = blockIdx.y * 64;
    const int KH  = CIN / 2;
    const int cb0 = blockIdx.z * KH;
    float* __restrict__ Zp = blockIdx.z ? Zp1 : Zp0;

    float acc[4][4];
    #pragma unroll
    for (int i = 0; i < 4; ++i)
        #pragma unroll
        for (int j = 0; j < 4; ++j) acc[i][j] = 0.0f;

    const int sr = tid >> 6;         // A staging row base (0..3), rows sr+4i
    const int sc = tid & 63;         // A staging col
    const int wo = tid >> 5;         // W staging: o_local base (0..7)
    const int wl = tid & 31;         // W staging: c_local

    for (int cb = cb0; cb < cb0 + KH; cb += 32) {
        #pragma unroll
        for (int i = 0; i < 8; ++i)
            s_a[sr + 4 * i][sc] = A[(size_t)(cb + sr + 4 * i) * HW + px0 + sc];
        #pragma unroll
        for (int i = 0; i < 8; ++i)
            s_w[wl][wo + 8 * i] = Wm[(size_t)(o0 + wo + 8 * i) * CIN + cb + wl];
        __syncthreads();
        #pragma unroll
        for (int cc = 0; cc < 32; ++cc) {
            float4 a4 = *(const float4*)&s_a[cc][tx * 4];
            float4 w4 = *(const float4*)&s_w[cc][ty * 4];
            acc[0][0] += w4.x * a4.x; acc[0][1] += w4.x * a4.y;
            acc[0][2] += w4.x * a4.z; acc[0][3] += w4.x * a4.w;
            acc[1][0] += w4.y * a4.x; acc[1][1] += w4.y * a4.y;
            acc[1][2] += w4.y * a4.z; acc[1][3] += w4.y * a4.w;
            acc[2][0] += w4.z * a4.x; acc[2][1] += w4.z * a4.y;
            acc[2][2] += w4.z * a4.z; acc[2][3] += w4.z * a4.w;
            acc[3][0] += w4.w * a4.x; acc[3][1] += w4.w * a4.y;
            acc[3][2] += w4.w * a4.z; acc[3][3] += w4.w * a4.w;
        }
        __syncthreads();
    }

    #pragma unroll
    for (int i = 0; i < 4; ++i) {
        float4 v = make_float4(acc[i][0], acc[i][1], acc[i][2], acc[i][3]);
        *(float4*)&Zp[(size_t)(o0 + ty * 4 + i) * HW + px0 + tx * 4] = v;
    }
}

// ---------------------------------------------------------------------------
// Combine split-K partials + BN stats:  Z = Zp0 + Zp1, accumulate per-channel
// (sum, sumsq) via wave reduce + atomics.  grid = (128 ch x 4 segments).
// ---------------------------------------------------------------------------
__global__ __launch_bounds__(256) void k_combine(
    const float* __restrict__ Zp0,
    const float* __restrict__ Zp1,
    float* __restrict__ Z,
    float* __restrict__ psum)        // 128 x {sum,sumsq}, pre-zeroed
{
    __shared__ float s_s[4], s_q[4];
    const int c   = blockIdx.x >> 2;
    const int seg = blockIdx.x & 3;
    const int tid = threadIdx.x;
    const size_t base = (size_t)c * HW + seg * 3072;
    float s = 0.0f, q = 0.0f;
    #pragma unroll
    for (int i = 0; i < 12; ++i) {
        float v = Zp0[base + tid + i * 256] + Zp1[base + tid + i * 256];
        Z[base + tid + i * 256] = v;
        s += v;
        q += v * v;
    }
    #pragma unroll
    for (int off = 32; off > 0; off >>= 1) {
        s += __shfl_down(s, off, 64);
        q += __shfl_down(q, off, 64);
    }
    if ((tid & 63) == 0) { s_s[tid >> 6] = s; s_q[tid >> 6] = q; }
    __syncthreads();
    if (tid == 0) {
        s = s_s[0] + s_s[1] + s_s[2] + s_s[3];
        q = s_q[0] + s_q[1] + s_q[2] + s_q[3];
        atomicAdd(&psum[2 * c],     s);
        atomicAdd(&psum[2 * c + 1], q);
    }
}

// ---------------------------------------------------------------------------
// Finalize BN params in place: (sum, sumsq) -> (scale, shift).  1 block.
// ---------------------------------------------------------------------------
__global__ void k_params(float* __restrict__ p,
                         const float* __restrict__ g,
                         const float* __restrict__ b)
{
    const int c = threadIdx.x;   // 128
    float s = p[2 * c], q = p[2 * c + 1];
    float mu  = s * (1.0f / HW);
    float var = q * (1.0f / HW) - mu * mu;
    float sc  = g[c] * rsqrtf(var + 1e-5f);
    p[2 * c]     = sc;
    p[2 * c + 1] = b[c] - mu * sc;
}

// ---------------------------------------------------------------------------
// Fused BN+LeakyReLU then depthwise 3x3 (pad 1).  One thread / output.
// ---------------------------------------------------------------------------
__global__ __launch_bounds__(256) void k_dw(
    const float* __restrict__ Z,
    const float* __restrict__ params,
    const float* __restrict__ dwgt,  // 128 x 9
    float* __restrict__ D)
{
    const int t = blockIdx.x * 256 + threadIdx.x;
    const int c = t / HW;
    const int p = t - c * HW;
    const int h = p / Wimg;
    const int w = p - h * Wimg;
    const float sc = params[2 * c];
    const float sh = params[2 * c + 1];
    float wk[9];
    #pragma unroll
    for (int k = 0; k < 9; ++k) wk[k] = dwgt[c * 9 + k];
    float acc = 0.0f;
    #pragma unroll
    for (int ky = 0; ky < 3; ++ky) {
        int hh = h + ky - 1;
        if (hh < 0 || hh >= Himg) continue;
        #pragma unroll
        for (int kx = 0; kx < 3; ++kx) {
            int ww = w + kx - 1;
            if (ww < 0 || ww >= Wimg) continue;
            float z = Z[(size_t)c * HW + hh * Wimg + ww];
            float y = z * sc + sh;
            y = (y >= 0.0f) ? y : 0.01f * y;
            acc += wk[ky * 3 + kx] * y;
        }
    }
    D[t] = acc;
}

// ---------------------------------------------------------------------------
// Final BN+LeakyReLU (fp32 out).
// ---------------------------------------------------------------------------
__global__ __launch_bounds__(256) void k_final(
    const float* __restrict__ Z,
    const float* __restrict__ params,
    float* __restrict__ out)
{
    const int t = blockIdx.x * 256 + threadIdx.x;
    const int c = t / HW;
    float v = Z[t] * params[2 * c] + params[2 * c + 1];
    v = (v >= 0.0f) ? v : 0.01f * v;
    out[t] = v;
}

// ---------------------------------------------------------------------------
extern "C" void kernel_launch(void* const* d_in, const int* in_sizes, int n_in,
                              void* d_out, int out_size, void* d_ws, size_t ws_size,
                              hipStream_t stream) {
    const float* x   = (const float*)d_in[0];
    const float* xr  = (const float*)d_in[1];
    const float* ro  = (const float*)d_in[2];
    const float* wr  = (const float*)d_in[3];
    const float* gr  = (const float*)d_in[4];
    const float* br  = (const float*)d_in[5];
    const float* dw1 = (const float*)d_in[6];
    const float* pw1 = (const float*)d_in[7];
    const float* g1  = (const float*)d_in[8];
    const float* b1  = (const float*)d_in[9];
    const float* dw2 = (const float*)d_in[10];
    const float* pw2 = (const float*)d_in[11];
    const float* g2  = (const float*)d_in[12];
    const float* b2  = (const float*)d_in[13];

    float* ws = (float*)d_ws;
    // A: 3,145,728 floats  (y0; later z|d pairs)
    // B: 1,572,864         (Zp0)
    // C: 1,572,864         (Zp1)
    float* A   = ws;
    float* B   = ws + 3145728;
    float* C   = ws + 4718592;
    float* y0  = A;
    float* zlo = A;                  // combined Z slots
    float* zhi = A + 1572864;        // d slots
    float* p1  = ws + 6291456;
    float* p2  = p1 + 256;
    float* p3  = p2 + 256;
    float* out = (float*)d_out;

    hipMemsetAsync(p1, 0, 768 * 4, stream);            // p1,p2,p3

    k_deform<<<dim3(192, 8), 256, 0, stream>>>(x, xr, ro, y0);
    k_pw<256><<<dim3(192, 2, 2), 256, 0, stream>>>(y0, wr, B, C);
    k_combine<<<512, 256, 0, stream>>>(B, C, zlo, p1); // y0 dead -> z1 = zlo
    k_params<<<1, 128, 0, stream>>>(p1, gr, br);
    k_dw<<<6144, 256, 0, stream>>>(zlo, p1, dw1, zhi); // d1 = zhi
    k_pw<128><<<dim3(192, 2, 2), 256, 0, stream>>>(zhi, pw1, B, C);
    k_combine<<<512, 256, 0, stream>>>(B, C, zlo, p2); // z2 = zlo (z1 dead)
    k_params<<<1, 128, 0, stream>>>(p2, g1, b1);
    k_dw<<<6144, 256, 0, stream>>>(zlo, p2, dw2, zhi); // d2 = zhi (d1 dead)
    k_pw<128><<<dim3(192, 2, 2), 256, 0, stream>>>(zhi, pw2, B, C);
    k_combine<<<512, 256, 0, stream>>>(B, C, zlo, p3); // z3 = zlo
    k_params<<<1, 128, 0, stream>>>(p3, g2, b2);
    k_final<<<6144, 256, 0, stream>>>(zlo, p3, out);
}

// Round 9
// 213.612 us; speedup vs baseline: 2.0584x; 1.0426x over previous
//
#include <hip/hip_runtime.h>
#include <hip/hip_bf16.h>

#define HW    12288
#define Wimg  192
#define Himg  64
#define Wpad  194
#define Ppad  12804   // 66*194

// ---------------------------------------------------------------------------
// K1: deformable gather, register-resident metadata.
// grid = (192 px tiles, 8 channel blocks of 32), 256 threads (4 waves x 8 ch).
// Key facts (proven, bit-exact vs reference):
//  - xo==0 taps have exactly zero weight -> only 6 taps (xo=+-1, yo=-1,0,1).
//  - per tap, the 4 bilinear candidates span <=3 consecutive indices b..b+2
//    (clamp is 1-Lipschitz), so merge weights into 3 slots.
// Each lane handles one pixel: 18 (idx,weight) pairs live in registers; the
// channel loop does 18 gathers + 24 FMA per channel.  No LDS at all.
// ---------------------------------------------------------------------------
__global__ __launch_bounds__(256) void k_deform(
    const float* __restrict__ x,     // 256 x HW
    const float* __restrict__ xr,    // HW
    const float* __restrict__ rout,  // 256 x 9
    float* __restrict__ y0)          // 256 x HW
{
    const int tile = blockIdx.x;     // 0..191
    const int cblk = blockIdx.y;     // 0..7
    const int pl   = threadIdx.x & 63;
    const int wv   = __builtin_amdgcn_readfirstlane(threadIdx.x >> 6);
    const int gp   = tile * 64 + pl;
    const int h = gp / Wimg, w = gp - h * Wimg;

    int   gi[6][3];
    float gw[6][3];
    const float off = 3.0f / (1.0f + expf(-xr[gp]));

    #pragma unroll
    for (int t = 0; t < 6; ++t) {
        const int xo = (t & 1) ? 1 : -1;
        const int yo = (t >> 1) - 1;
        // replicate reference math exactly (same as rounds 2-8)
        float ov  = off * (float)xo;
        int   iv  = yo * Wpad;
        int   pre = (h + 1) * Wpad + (w + 1) + xo + iv;
        float after = (float)(pre + iv) + ov;
        int fl = (int)floorf(ov);
        int ce = (int)ceilf(ov);
        int av_f  = min(max(pre + fl + iv, 0), Ppad - 1);
        int av_f1 = min(max(av_f + xo,    0), Ppad - 1);
        int av_c  = min(max(pre + ce + iv, 0), Ppad - 1);
        int av_c1 = min(max(av_c + xo,    0), Ppad - 1);
        float wf  = fabsf(after - (float)av_f);
        float wf1 = fabsf((float)av_f1 - after);
        float wc1 = fabsf(after - (float)av_c1);
        float wc  = fabsf((float)av_c - after);
        float s1 = wf  * (1.0f / Wpad);
        float s2 = wc1 * (1.0f / Wpad);
        int   i4[4] = { av_f, av_f1, av_c1, av_c };
        float w4[4] = { s1 * wf, s1 * wf1, s2 * wc1, s2 * wc };
        int b = min(min(i4[0], i4[1]), min(i4[2], i4[3]));
        #pragma unroll
        for (int s = 0; s < 3; ++s) {
            float ws = 0.0f;
            #pragma unroll
            for (int j = 0; j < 4; ++j)
                ws += (i4[j] == b + s) ? w4[j] : 0.0f;
            // translate padded-grid index -> unpadded x index; pad cells are
            // zero in the reference's x_padded, so zero the weight instead.
            int av = b + s;
            int r  = av / Wpad;
            int cc = av - r * Wpad;
            bool inb = (r >= 1) && (r <= Himg) && (cc >= 1) && (cc <= Wimg);
            gi[t][s] = inb ? ((r - 1) * Wimg + (cc - 1)) : 0;
            gw[t][s] = inb ? ws : 0.0f;
        }
    }

    // tap t -> rout column: xo=-1 -> 3*(yo+1), xo=+1 -> 3*(yo+1)+2
    const int c0 = cblk * 32 + wv * 8;
    for (int i = 0; i < 8; ++i) {
        const int c = c0 + i;
        const float* xc = x + (size_t)c * HW;
        const float* rc = rout + c * 9;
        float acc = 0.0f;
        #pragma unroll
        for (int t = 0; t < 6; ++t) {
            float part = gw[t][0] * xc[gi[t][0]]
                       + gw[t][1] * xc[gi[t][1]]
                       + gw[t][2] * xc[gi[t][2]];
            const int k = 3 * (t >> 1) + ((t & 1) ? 2 : 0);
            acc += rc[k] * part;
        }
        y0[(size_t)c * HW + gp] = acc;
    }
}

// ---------------------------------------------------------------------------
// Pointwise GEMM, split-K into partial buffers (NO atomics):
//   Zp[z][128 x HW] = W[128, K-half z] * A[K-half z, HW]
// Block = 64 px x 64 outs, grid (192, 2, 2) = 768 blocks.  256 threads, 4x4
// register tile, 32-deep LDS chunks.  W transpose-staged in LDS (+4 pad).
// ---------------------------------------------------------------------------
template <int CIN>
__global__ __launch_bounds__(256) void k_pw(
    const float* __restrict__ A,     // CIN x HW
    const float* __restrict__ Wm,    // 128 x CIN (original layout)
    float* __restrict__ Zp0,         // partial for K-half 0
    float* __restrict__ Zp1)         // partial for K-half 1
{
    __shared__ float s_a[32][64];
    __shared__ float s_w[32][68];    // [c_local][o_local], +4 pad
    const int tid = threadIdx.x;
    const int tx  = tid & 15;        // px group (4 px)
    const int ty  = tid >> 4;        // o group (4 outs)
    const int px0 = blockIdx.x * 64;
    const int o0  = blockIdx.y * 64;
    const int KH  = CIN / 2;
    const int cb0 = blockIdx.z * KH;
    float* __restrict__ Zp = blockIdx.z ? Zp1 : Zp0;

    float acc[4][4];
    #pragma unroll
    for (int i = 0; i < 4; ++i)
        #pragma unroll
        for (int j = 0; j < 4; ++j) acc[i][j] = 0.0f;

    const int sr = tid >> 6;         // A staging row base (0..3), rows sr+4i
    const int sc = tid & 63;         // A staging col
    const int wo = tid >> 5;         // W staging: o_local base (0..7)
    const int wl = tid & 31;         // W staging: c_local

    for (int cb = cb0; cb < cb0 + KH; cb += 32) {
        #pragma unroll
        for (int i = 0; i < 8; ++i)
            s_a[sr + 4 * i][sc] = A[(size_t)(cb + sr + 4 * i) * HW + px0 + sc];
        #pragma unroll
        for (int i = 0; i < 8; ++i)
            s_w[wl][wo + 8 * i] = Wm[(size_t)(o0 + wo + 8 * i) * CIN + cb + wl];
        __syncthreads();
        #pragma unroll
        for (int cc = 0; cc < 32; ++cc) {
            float4 a4 = *(const float4*)&s_a[cc][tx * 4];
            float4 w4 = *(const float4*)&s_w[cc][ty * 4];
            acc[0][0] += w4.x * a4.x; acc[0][1] += w4.x * a4.y;
            acc[0][2] += w4.x * a4.z; acc[0][3] += w4.x * a4.w;
            acc[1][0] += w4.y * a4.x; acc[1][1] += w4.y * a4.y;
            acc[1][2] += w4.y * a4.z; acc[1][3] += w4.y * a4.w;
            acc[2][0] += w4.z * a4.x; acc[2][1] += w4.z * a4.y;
            acc[2][2] += w4.z * a4.z; acc[2][3] += w4.z * a4.w;
            acc[3][0] += w4.w * a4.x; acc[3][1] += w4.w * a4.y;
            acc[3][2] += w4.w * a4.z; acc[3][3] += w4.w * a4.w;
        }
        __syncthreads();
    }

    #pragma unroll
    for (int i = 0; i < 4; ++i) {
        float4 v = make_float4(acc[i][0], acc[i][1], acc[i][2], acc[i][3]);
        *(float4*)&Zp[(size_t)(o0 + ty * 4 + i) * HW + px0 + tx * 4] = v;
    }
}

// ---------------------------------------------------------------------------
// Combine split-K partials + BN stats (float4):  Z = Zp0 + Zp1.
// grid = (128 ch x 4 segments).
// ---------------------------------------------------------------------------
__global__ __launch_bounds__(256) void k_combine(
    const float* __restrict__ Zp0,
    const float* __restrict__ Zp1,
    float* __restrict__ Z,
    float* __restrict__ psum)        // 128 x {sum,sumsq}, pre-zeroed
{
    __shared__ float s_s[4], s_q[4];
    const int c   = blockIdx.x >> 2;
    const int seg = blockIdx.x & 3;
    const int tid = threadIdx.x;
    const size_t base = (size_t)c * HW + seg * 3072;
    const float4* a4 = (const float4*)(Zp0 + base);
    const float4* b4 = (const float4*)(Zp1 + base);
    float4*       z4 = (float4*)(Z + base);
    float s = 0.0f, q = 0.0f;
    #pragma unroll
    for (int i = 0; i < 3; ++i) {
        float4 a = a4[tid + i * 256];
        float4 b = b4[tid + i * 256];
        float4 v = make_float4(a.x + b.x, a.y + b.y, a.z + b.z, a.w + b.w);
        z4[tid + i * 256] = v;
        s += v.x + v.y + v.z + v.w;
        q += v.x * v.x + v.y * v.y + v.z * v.z + v.w * v.w;
    }
    #pragma unroll
    for (int off = 32; off > 0; off >>= 1) {
        s += __shfl_down(s, off, 64);
        q += __shfl_down(q, off, 64);
    }
    if ((tid & 63) == 0) { s_s[tid >> 6] = s; s_q[tid >> 6] = q; }
    __syncthreads();
    if (tid == 0) {
        s = s_s[0] + s_s[1] + s_s[2] + s_s[3];
        q = s_q[0] + s_q[1] + s_q[2] + s_q[3];
        atomicAdd(&psum[2 * c],     s);
        atomicAdd(&psum[2 * c + 1], q);
    }
}

// ---------------------------------------------------------------------------
// Finalize BN params in place: (sum, sumsq) -> (scale, shift).  1 block.
// ---------------------------------------------------------------------------
__global__ void k_params(float* __restrict__ p,
                         const float* __restrict__ g,
                         const float* __restrict__ b)
{
    const int c = threadIdx.x;   // 128
    float s = p[2 * c], q = p[2 * c + 1];
    float mu  = s * (1.0f / HW);
    float var = q * (1.0f / HW) - mu * mu;
    float sc  = g[c] * rsqrtf(var + 1e-5f);
    p[2 * c]     = sc;
    p[2 * c + 1] = b[c] - mu * sc;
}

// ---------------------------------------------------------------------------
// Fused BN+LeakyReLU then depthwise 3x3 (pad 1).  One thread / output.
// ---------------------------------------------------------------------------
__global__ __launch_bounds__(256) void k_dw(
    const float* __restrict__ Z,
    const float* __restrict__ params,
    const float* __restrict__ dwgt,  // 128 x 9
    float* __restrict__ D)
{
    const int t = blockIdx.x * 256 + threadIdx.x;
    const int c = t / HW;
    const int p = t - c * HW;
    const int h = p / Wimg;
    const int w = p - h * Wimg;
    const float sc = params[2 * c];
    const float sh = params[2 * c + 1];
    float wk[9];
    #pragma unroll
    for (int k = 0; k < 9; ++k) wk[k] = dwgt[c * 9 + k];
    float acc = 0.0f;
    #pragma unroll
    for (int ky = 0; ky < 3; ++ky) {
        int hh = h + ky - 1;
        if (hh < 0 || hh >= Himg) continue;
        #pragma unroll
        for (int kx = 0; kx < 3; ++kx) {
            int ww = w + kx - 1;
            if (ww < 0 || ww >= Wimg) continue;
            float z = Z[(size_t)c * HW + hh * Wimg + ww];
            float y = z * sc + sh;
            y = (y >= 0.0f) ? y : 0.01f * y;
            acc += wk[ky * 3 + kx] * y;
        }
    }
    D[t] = acc;
}

// ---------------------------------------------------------------------------
// Final BN+LeakyReLU, float4.  grid = 1536.
// ---------------------------------------------------------------------------
__global__ __launch_bounds__(256) void k_final(
    const float4* __restrict__ Z,
    const float* __restrict__ params,
    float4* __restrict__ out)
{
    const int f = blockIdx.x * 256 + threadIdx.x;   // 0..393215
    const int c = f / 3072;                          // HW/4 = 3072
    const float sc = params[2 * c];
    const float sh = params[2 * c + 1];
    float4 z = Z[f];
    float4 v;
    v.x = z.x * sc + sh; v.x = (v.x >= 0.0f) ? v.x : 0.01f * v.x;
    v.y = z.y * sc + sh; v.y = (v.y >= 0.0f) ? v.y : 0.01f * v.y;
    v.z = z.z * sc + sh; v.z = (v.z >= 0.0f) ? v.z : 0.01f * v.z;
    v.w = z.w * sc + sh; v.w = (v.w >= 0.0f) ? v.w : 0.01f * v.w;
    out[f] = v;
}

// ---------------------------------------------------------------------------
extern "C" void kernel_launch(void* const* d_in, const int* in_sizes, int n_in,
                              void* d_out, int out_size, void* d_ws, size_t ws_size,
                              hipStream_t stream) {
    const float* x   = (const float*)d_in[0];
    const float* xr  = (const float*)d_in[1];
    const float* ro  = (const float*)d_in[2];
    const float* wr  = (const float*)d_in[3];
    const float* gr  = (const float*)d_in[4];
    const float* br  = (const float*)d_in[5];
    const float* dw1 = (const float*)d_in[6];
    const float* pw1 = (const float*)d_in[7];
    const float* g1  = (const float*)d_in[8];
    const float* b1  = (const float*)d_in[9];
    const float* dw2 = (const float*)d_in[10];
    const float* pw2 = (const float*)d_in[11];
    const float* g2  = (const float*)d_in[12];
    const float* b2  = (const float*)d_in[13];

    float* ws = (float*)d_ws;
    // A: 3,145,728 floats  (y0; later z|d pairs)
    // B: 1,572,864         (Zp0)
    // C: 1,572,864         (Zp1)
    float* A   = ws;
    float* B   = ws + 3145728;
    float* C   = ws + 4718592;
    float* y0  = A;
    float* zlo = A;                  // combined Z slots
    float* zhi = A + 1572864;        // d slots
    float* p1  = ws + 6291456;
    float* p2  = p1 + 256;
    float* p3  = p2 + 256;
    float* out = (float*)d_out;

    hipMemsetAsync(p1, 0, 768 * 4, stream);            // p1,p2,p3

    k_deform<<<dim3(192, 8), 256, 0, stream>>>(x, xr, ro, y0);
    k_pw<256><<<dim3(192, 2, 2), 256, 0, stream>>>(y0, wr, B, C);
    k_combine<<<512, 256, 0, stream>>>(B, C, zlo, p1); // y0 dead -> z1 = zlo
    k_params<<<1, 128, 0, stream>>>(p1, gr, br);
    k_dw<<<6144, 256, 0, stream>>>(zlo, p1, dw1, zhi); // d1 = zhi
    k_pw<128><<<dim3(192, 2, 2), 256, 0, stream>>>(zhi, pw1, B, C);
    k_combine<<<512, 256, 0, stream>>>(B, C, zlo, p2); // z2 = zlo (z1 dead)
    k_params<<<1, 128, 0, stream>>>(p2, g1, b1);
    k_dw<<<6144, 256, 0, stream>>>(zlo, p2, dw2, zhi); // d2 = zhi (d1 dead)
    k_pw<128><<<dim3(192, 2, 2), 256, 0, stream>>>(zhi, pw2, B, C);
    k_combine<<<512, 256, 0, stream>>>(B, C, zlo, p3); // z3 = zlo
    k_params<<<1, 128, 0, stream>>>(p3, g2, b2);
    k_final<<<1536, 256, 0, stream>>>((const float4*)zlo, p3, (float4*)out);
}

// Round 10
// 203.025 us; speedup vs baseline: 2.1657x; 1.0521x over previous
//
#include <hip/hip_runtime.h>
#include <hip/hip_bf16.h>

#define HW    12288
#define Wimg  192
#define Himg  64
#define Wpad  194
#define Ppad  12804   // 66*194

// ---------------------------------------------------------------------------
// K1: deformable gather, register-resident metadata.
// grid = (8 channel blocks, 192 px tiles) -- cblk fastest so the round-robin
// block->XCD mapping pins each XCD to 32 channels (1.57 MB of x, L2-resident).
// 256 threads = 4 waves x 8 ch.  Per lane: 18 (idx,w) pairs in registers
// (xo==0 taps are exactly zero; 4 bilinear candidates span <=3 consecutive
// indices).  18 gathers + 24 FMA per channel, no LDS.
// ---------------------------------------------------------------------------
__global__ __launch_bounds__(256) void k_deform(
    const float* __restrict__ x,     // 256 x HW
    const float* __restrict__ xr,    // HW
    const float* __restrict__ rout,  // 256 x 9
    float* __restrict__ y0)          // 256 x HW
{
    const int cblk = blockIdx.x;     // 0..7   (fastest -> XCD id)
    const int tile = blockIdx.y;     // 0..191
    const int pl   = threadIdx.x & 63;
    const int wv   = __builtin_amdgcn_readfirstlane(threadIdx.x >> 6);
    const int gp   = tile * 64 + pl;
    const int h = gp / Wimg, w = gp - h * Wimg;

    int   gi[6][3];
    float gw[6][3];
    const float off = 3.0f / (1.0f + expf(-xr[gp]));

    #pragma unroll
    for (int t = 0; t < 6; ++t) {
        const int xo = (t & 1) ? 1 : -1;
        const int yo = (t >> 1) - 1;
        // replicate reference math exactly (same as rounds 2-9)
        float ov  = off * (float)xo;
        int   iv  = yo * Wpad;
        int   pre = (h + 1) * Wpad + (w + 1) + xo + iv;
        float after = (float)(pre + iv) + ov;
        int fl = (int)floorf(ov);
        int ce = (int)ceilf(ov);
        int av_f  = min(max(pre + fl + iv, 0), Ppad - 1);
        int av_f1 = min(max(av_f + xo,    0), Ppad - 1);
        int av_c  = min(max(pre + ce + iv, 0), Ppad - 1);
        int av_c1 = min(max(av_c + xo,    0), Ppad - 1);
        float wf  = fabsf(after - (float)av_f);
        float wf1 = fabsf((float)av_f1 - after);
        float wc1 = fabsf(after - (float)av_c1);
        float wc  = fabsf((float)av_c - after);
        float s1 = wf  * (1.0f / Wpad);
        float s2 = wc1 * (1.0f / Wpad);
        int   i4[4] = { av_f, av_f1, av_c1, av_c };
        float w4[4] = { s1 * wf, s1 * wf1, s2 * wc1, s2 * wc };
        int b = min(min(i4[0], i4[1]), min(i4[2], i4[3]));
        #pragma unroll
        for (int s = 0; s < 3; ++s) {
            float ws = 0.0f;
            #pragma unroll
            for (int j = 0; j < 4; ++j)
                ws += (i4[j] == b + s) ? w4[j] : 0.0f;
            int av = b + s;
            int r  = av / Wpad;
            int cc = av - r * Wpad;
            bool inb = (r >= 1) && (r <= Himg) && (cc >= 1) && (cc <= Wimg);
            gi[t][s] = inb ? ((r - 1) * Wimg + (cc - 1)) : 0;
            gw[t][s] = inb ? ws : 0.0f;
        }
    }

    // tap t -> rout column: xo=-1 -> 3*(yo+1), xo=+1 -> 3*(yo+1)+2
    const int c0 = cblk * 32 + wv * 8;
    for (int i = 0; i < 8; ++i) {
        const int c = c0 + i;
        const float* xc = x + (size_t)c * HW;
        const float* rc = rout + c * 9;
        float acc = 0.0f;
        #pragma unroll
        for (int t = 0; t < 6; ++t) {
            float part = gw[t][0] * xc[gi[t][0]]
                       + gw[t][1] * xc[gi[t][1]]
                       + gw[t][2] * xc[gi[t][2]];
            const int k = 3 * (t >> 1) + ((t & 1) ? 2 : 0);
            acc += rc[k] * part;
        }
        y0[(size_t)c * HW + gp] = acc;
    }
}

// ---------------------------------------------------------------------------
// Pointwise GEMM, split-K into partial buffers (NO atomics):
//   Zp[z][128 x HW] = W[128, K-half z] * A[K-half z, HW]
// Block = 64 px x 64 outs, grid (192, 2, 2) = 768 blocks.  256 threads, 4x4
// register tile, 32-deep LDS chunks.  W transpose-staged in LDS (+4 pad).
// ---------------------------------------------------------------------------
template <int CIN>
__global__ __launch_bounds__(256) void k_pw(
    const float* __restrict__ A,     // CIN x HW
    const float* __restrict__ Wm,    // 128 x CIN (original layout)
    float* __restrict__ Zp0,         // partial for K-half 0
    float* __restrict__ Zp1)         // partial for K-half 1
{
    __shared__ float s_a[32][64];
    __shared__ float s_w[32][68];    // [c_local][o_local], +4 pad
    const int tid = threadIdx.x;
    const int tx  = tid & 15;        // px group (4 px)
    const int ty  = tid >> 4;        // o group (4 outs)
    const int px0 = blockIdx.x * 64;
    const int o0  = blockIdx.y * 64;
    const int KH  = CIN / 2;
    const int cb0 = blockIdx.z * KH;
    float* __restrict__ Zp = blockIdx.z ? Zp1 : Zp0;

    float acc[4][4];
    #pragma unroll
    for (int i = 0; i < 4; ++i)
        #pragma unroll
        for (int j = 0; j < 4; ++j) acc[i][j] = 0.0f;

    const int sr = tid >> 6;         // A staging row base (0..3), rows sr+4i
    const int sc = tid & 63;         // A staging col
    const int wo = tid >> 5;         // W staging: o_local base (0..7)
    const int wl = tid & 31;         // W staging: c_local

    for (int cb = cb0; cb < cb0 + KH; cb += 32) {
        #pragma unroll
        for (int i = 0; i < 8; ++i)
            s_a[sr + 4 * i][sc] = A[(size_t)(cb + sr + 4 * i) * HW + px0 + sc];
        #pragma unroll
        for (int i = 0; i < 8; ++i)
            s_w[wl][wo + 8 * i] = Wm[(size_t)(o0 + wo + 8 * i) * CIN + cb + wl];
        __syncthreads();
        #pragma unroll
        for (int cc = 0; cc < 32; ++cc) {
            float4 a4 = *(const float4*)&s_a[cc][tx * 4];
            float4 w4 = *(const float4*)&s_w[cc][ty * 4];
            acc[0][0] += w4.x * a4.x; acc[0][1] += w4.x * a4.y;
            acc[0][2] += w4.x * a4.z; acc[0][3] += w4.x * a4.w;
            acc[1][0] += w4.y * a4.x; acc[1][1] += w4.y * a4.y;
            acc[1][2] += w4.y * a4.z; acc[1][3] += w4.y * a4.w;
            acc[2][0] += w4.z * a4.x; acc[2][1] += w4.z * a4.y;
            acc[2][2] += w4.z * a4.z; acc[2][3] += w4.z * a4.w;
            acc[3][0] += w4.w * a4.x; acc[3][1] += w4.w * a4.y;
            acc[3][2] += w4.w * a4.z; acc[3][3] += w4.w * a4.w;
        }
        __syncthreads();
    }

    #pragma unroll
    for (int i = 0; i < 4; ++i) {
        float4 v = make_float4(acc[i][0], acc[i][1], acc[i][2], acc[i][3]);
        *(float4*)&Zp[(size_t)(o0 + ty * 4 + i) * HW + px0 + tx * 4] = v;
    }
}

// ---------------------------------------------------------------------------
// Combine split-K partials + BN stats (float4):  Z = Zp0 + Zp1.
// grid = (128 ch x 4 segments).
// ---------------------------------------------------------------------------
__global__ __launch_bounds__(256) void k_combine(
    const float* __restrict__ Zp0,
    const float* __restrict__ Zp1,
    float* __restrict__ Z,
    float* __restrict__ psum)        // 128 x {sum,sumsq}, pre-zeroed
{
    __shared__ float s_s[4], s_q[4];
    const int c   = blockIdx.x >> 2;
    const int seg = blockIdx.x & 3;
    const int tid = threadIdx.x;
    const size_t base = (size_t)c * HW + seg * 3072;
    const float4* a4 = (const float4*)(Zp0 + base);
    const float4* b4 = (const float4*)(Zp1 + base);
    float4*       z4 = (float4*)(Z + base);
    float s = 0.0f, q = 0.0f;
    #pragma unroll
    for (int i = 0; i < 3; ++i) {
        float4 a = a4[tid + i * 256];
        float4 b = b4[tid + i * 256];
        float4 v = make_float4(a.x + b.x, a.y + b.y, a.z + b.z, a.w + b.w);
        z4[tid + i * 256] = v;
        s += v.x + v.y + v.z + v.w;
        q += v.x * v.x + v.y * v.y + v.z * v.z + v.w * v.w;
    }
    #pragma unroll
    for (int off = 32; off > 0; off >>= 1) {
        s += __shfl_down(s, off, 64);
        q += __shfl_down(q, off, 64);
    }
    if ((tid & 63) == 0) { s_s[tid >> 6] = s; s_q[tid >> 6] = q; }
    __syncthreads();
    if (tid == 0) {
        s = s_s[0] + s_s[1] + s_s[2] + s_s[3];
        q = s_q[0] + s_q[1] + s_q[2] + s_q[3];
        atomicAdd(&psum[2 * c],     s);
        atomicAdd(&psum[2 * c + 1], q);
    }
}

// ---------------------------------------------------------------------------
// Finalize BN params in place: (sum, sumsq) -> (scale, shift).  1 block.
// ---------------------------------------------------------------------------
__global__ void k_params(float* __restrict__ p,
                         const float* __restrict__ g,
                         const float* __restrict__ b)
{
    const int c = threadIdx.x;   // 128
    float s = p[2 * c], q = p[2 * c + 1];
    float mu  = s * (1.0f / HW);
    float var = q * (1.0f / HW) - mu * mu;
    float sc  = g[c] * rsqrtf(var + 1e-5f);
    p[2 * c]     = sc;
    p[2 * c + 1] = b[c] - mu * sc;
}

// ---------------------------------------------------------------------------
// Fused BN+LeakyReLU then depthwise 3x3 (zero pad 1).  4 px / thread:
// 18 loads -> 4 outputs (vs 36), float4 store.  grid = 1536.
// Note: conv zero-pads the POST-activation map, so OOB taps contribute 0
// (not act(0)).
// ---------------------------------------------------------------------------
__global__ __launch_bounds__(256) void k_dw(
    const float* __restrict__ Z,
    const float* __restrict__ params,
    const float* __restrict__ dwgt,  // 128 x 9
    float4* __restrict__ D)
{
    const int t  = blockIdx.x * 256 + threadIdx.x;  // 0..393215
    const int c  = t / 3072;                        // HW/4 groups per channel
    const int g  = t - c * 3072;
    const int h  = g / 48;                          // 192/4 = 48 groups/row
    const int w0 = (g - h * 48) << 2;
    const float sc = params[2 * c];
    const float sh = params[2 * c + 1];
    float wk[9];
    #pragma unroll
    for (int k = 0; k < 9; ++k) wk[k] = dwgt[c * 9 + k];

    const float* zc = Z + (size_t)c * HW;
    float v[3][6];
    #pragma unroll
    for (int ky = 0; ky < 3; ++ky) {
        const int hh  = h + ky - 1;
        const bool rin = (hh >= 0) && (hh < Himg);
        #pragma unroll
        for (int j = 0; j < 6; ++j) {
            const int ww = w0 - 1 + j;
            const bool in = rin && (ww >= 0) && (ww < Wimg);
            float z = in ? zc[hh * Wimg + ww] : 0.0f;
            float y = z * sc + sh;
            y = (y >= 0.0f) ? y : 0.01f * y;
            v[ky][j] = in ? y : 0.0f;
        }
    }

    float o[4];
    #pragma unroll
    for (int j = 0; j < 4; ++j) {
        float a = 0.0f;
        #pragma unroll
        for (int ky = 0; ky < 3; ++ky)
            #pragma unroll
            for (int kx = 0; kx < 3; ++kx)
                a += wk[ky * 3 + kx] * v[ky][j + kx];
        o[j] = a;
    }
    D[t] = make_float4(o[0], o[1], o[2], o[3]);
}

// ---------------------------------------------------------------------------
// Final BN+LeakyReLU, float4.  grid = 1536.
// ---------------------------------------------------------------------------
__global__ __launch_bounds__(256) void k_final(
    const float4* __restrict__ Z,
    const float* __restrict__ params,
    float4* __restrict__ out)
{
    const int f = blockIdx.x * 256 + threadIdx.x;   // 0..393215
    const int c = f / 3072;                          // HW/4 = 3072
    const float sc = params[2 * c];
    const float sh = params[2 * c + 1];
    float4 z = Z[f];
    float4 v;
    v.x = z.x * sc + sh; v.x = (v.x >= 0.0f) ? v.x : 0.01f * v.x;
    v.y = z.y * sc + sh; v.y = (v.y >= 0.0f) ? v.y : 0.01f * v.y;
    v.z = z.z * sc + sh; v.z = (v.z >= 0.0f) ? v.z : 0.01f * v.z;
    v.w = z.w * sc + sh; v.w = (v.w >= 0.0f) ? v.w : 0.01f * v.w;
    out[f] = v;
}

// ---------------------------------------------------------------------------
extern "C" void kernel_launch(void* const* d_in, const int* in_sizes, int n_in,
                              void* d_out, int out_size, void* d_ws, size_t ws_size,
                              hipStream_t stream) {
    const float* x   = (const float*)d_in[0];
    const float* xr  = (const float*)d_in[1];
    const float* ro  = (const float*)d_in[2];
    const float* wr  = (const float*)d_in[3];
    const float* gr  = (const float*)d_in[4];
    const float* br  = (const float*)d_in[5];
    const float* dw1 = (const float*)d_in[6];
    const float* pw1 = (const float*)d_in[7];
    const float* g1  = (const float*)d_in[8];
    const float* b1  = (const float*)d_in[9];
    const float* dw2 = (const float*)d_in[10];
    const float* pw2 = (const float*)d_in[11];
    const float* g2  = (const float*)d_in[12];
    const float* b2  = (const float*)d_in[13];

    float* ws = (float*)d_ws;
    // A: 3,145,728 floats  (y0; later z|d pairs)
    // B: 1,572,864         (Zp0)
    // C: 1,572,864         (Zp1)
    float* A   = ws;
    float* B   = ws + 3145728;
    float* C   = ws + 4718592;
    float* y0  = A;
    float* zlo = A;                  // combined Z slots
    float* zhi = A + 1572864;        // d slots
    float* p1  = ws + 6291456;
    float* p2  = p1 + 256;
    float* p3  = p2 + 256;
    float* out = (float*)d_out;

    hipMemsetAsync(p1, 0, 768 * 4, stream);            // p1,p2,p3

    k_deform<<<dim3(8, 192), 256, 0, stream>>>(x, xr, ro, y0);
    k_pw<256><<<dim3(192, 2, 2), 256, 0, stream>>>(y0, wr, B, C);
    k_combine<<<512, 256, 0, stream>>>(B, C, zlo, p1); // y0 dead -> z1 = zlo
    k_params<<<1, 128, 0, stream>>>(p1, gr, br);
    k_dw<<<1536, 256, 0, stream>>>(zlo, p1, dw1, (float4*)zhi); // d1 = zhi
    k_pw<128><<<dim3(192, 2, 2), 256, 0, stream>>>(zhi, pw1, B, C);
    k_combine<<<512, 256, 0, stream>>>(B, C, zlo, p2); // z2 = zlo (z1 dead)
    k_params<<<1, 128, 0, stream>>>(p2, g1, b1);
    k_dw<<<1536, 256, 0, stream>>>(zlo, p2, dw2, (float4*)zhi); // d2 = zhi
    k_pw<128><<<dim3(192, 2, 2), 256, 0, stream>>>(zhi, pw2, B, C);
    k_combine<<<512, 256, 0, stream>>>(B, C, zlo, p3); // z3 = zlo
    k_params<<<1, 128, 0, stream>>>(p3, g2, b2);
    k_final<<<1536, 256, 0, stream>>>((const float4*)zlo, p3, (float4*)out);
}

// Round 11
// 198.758 us; speedup vs baseline: 2.2122x; 1.0215x over previous
//
#include <hip/hip_runtime.h>
#include <hip/hip_bf16.h>

#define HW    12288
#define Wimg  192
#define Himg  64
#define Wpad  194
#define Ppad  12804   // 66*194

// ---------------------------------------------------------------------------
// K1: deformable gather, register-resident metadata + software-pipelined
// channel loop.  grid = (8 channel blocks, 192 px tiles) -- cblk fastest so
// the round-robin block->XCD mapping pins each XCD to 32 channels (1.57 MB of
// x, L2-resident; FETCH_SIZE 6.4 MB measured R10).
// __launch_bounds__(256,4): 16 waves/CU (same 50% occupancy as R10) but VGPR
// cap 128 instead of 32 -> 18+ gathers in flight per wave (R10's VGPR=32
// serialized the gathers; 450 GB/s, VALU 21%).
// ---------------------------------------------------------------------------
__global__ __launch_bounds__(256, 4) void k_deform(
    const float* __restrict__ x,     // 256 x HW
    const float* __restrict__ xr,    // HW
    const float* __restrict__ rout,  // 256 x 9
    float* __restrict__ y0)          // 256 x HW
{
    const int cblk = blockIdx.x;     // 0..7   (fastest -> XCD id)
    const int tile = blockIdx.y;     // 0..191
    const int pl   = threadIdx.x & 63;
    const int wv   = __builtin_amdgcn_readfirstlane(threadIdx.x >> 6);
    const int gp   = tile * 64 + pl;
    const int h = gp / Wimg, w = gp - h * Wimg;

    int   gi[6][3];
    float gw[6][3];
    const float off = 3.0f / (1.0f + expf(-xr[gp]));

    #pragma unroll
    for (int t = 0; t < 6; ++t) {
        const int xo = (t & 1) ? 1 : -1;
        const int yo = (t >> 1) - 1;
        // replicate reference math exactly (same as rounds 2-10)
        float ov  = off * (float)xo;
        int   iv  = yo * Wpad;
        int   pre = (h + 1) * Wpad + (w + 1) + xo + iv;
        float after = (float)(pre + iv) + ov;
        int fl = (int)floorf(ov);
        int ce = (int)ceilf(ov);
        int av_f  = min(max(pre + fl + iv, 0), Ppad - 1);
        int av_f1 = min(max(av_f + xo,    0), Ppad - 1);
        int av_c  = min(max(pre + ce + iv, 0), Ppad - 1);
        int av_c1 = min(max(av_c + xo,    0), Ppad - 1);
        float wf  = fabsf(after - (float)av_f);
        float wf1 = fabsf((float)av_f1 - after);
        float wc1 = fabsf(after - (float)av_c1);
        float wc  = fabsf((float)av_c - after);
        float s1 = wf  * (1.0f / Wpad);
        float s2 = wc1 * (1.0f / Wpad);
        int   i4[4] = { av_f, av_f1, av_c1, av_c };
        float w4[4] = { s1 * wf, s1 * wf1, s2 * wc1, s2 * wc };
        int b = min(min(i4[0], i4[1]), min(i4[2], i4[3]));
        #pragma unroll
        for (int s = 0; s < 3; ++s) {
            float ws = 0.0f;
            #pragma unroll
            for (int j = 0; j < 4; ++j)
                ws += (i4[j] == b + s) ? w4[j] : 0.0f;
            int av = b + s;
            int r  = av / Wpad;
            int cc = av - r * Wpad;
            bool inb = (r >= 1) && (r <= Himg) && (cc >= 1) && (cc <= Wimg);
            gi[t][s] = inb ? ((r - 1) * Wimg + (cc - 1)) : 0;
            gw[t][s] = inb ? ws : 0.0f;
        }
    }

    // tap t -> rout column: xo=-1 -> 3*(yo+1), xo=+1 -> 3*(yo+1)+2
    const int c0 = cblk * 32 + wv * 8;

    float cur[18], nxt[18];
    {
        const float* xc = x + (size_t)c0 * HW;
        #pragma unroll
        for (int u = 0; u < 18; ++u)
            cur[u] = xc[gi[u / 3][u % 3]];
    }
    #pragma unroll
    for (int i = 0; i < 8; ++i) {
        if (i < 7) {
            const float* xn = x + (size_t)(c0 + i + 1) * HW;
            #pragma unroll
            for (int u = 0; u < 18; ++u)
                nxt[u] = xn[gi[u / 3][u % 3]];
        }
        const float* rc = rout + (c0 + i) * 9;
        float acc = 0.0f;
        #pragma unroll
        for (int t = 0; t < 6; ++t) {
            float part = gw[t][0] * cur[3 * t]
                       + gw[t][1] * cur[3 * t + 1]
                       + gw[t][2] * cur[3 * t + 2];
            const int k = 3 * (t >> 1) + ((t & 1) ? 2 : 0);
            acc += rc[k] * part;
        }
        y0[(size_t)(c0 + i) * HW + gp] = acc;
        #pragma unroll
        for (int u = 0; u < 18; ++u) cur[u] = nxt[u];
    }
}

// ---------------------------------------------------------------------------
// Pointwise GEMM, split-K into partial buffers (NO atomics):
//   Zp[z][128 x HW] = W[128, K-half z] * A[K-half z, HW]
// Block = 64 px x 64 outs, grid (192, 2, 2) = 768 blocks.  256 threads, 4x4
// register tile, 32-deep LDS chunks.  W transpose-staged in LDS (+4 pad).
// ---------------------------------------------------------------------------
template <int CIN>
__global__ __launch_bounds__(256) void k_pw(
    const float* __restrict__ A,     // CIN x HW
    const float* __restrict__ Wm,    // 128 x CIN (original layout)
    float* __restrict__ Zp0,         // partial for K-half 0
    float* __restrict__ Zp1)         // partial for K-half 1
{
    __shared__ float s_a[32][64];
    __shared__ float s_w[32][68];    // [c_local][o_local], +4 pad
    const int tid = threadIdx.x;
    const int tx  = tid & 15;        // px group (4 px)
    const int ty  = tid >> 4;        // o group (4 outs)
    const int px0 = blockIdx.x * 64;
    const int o0  = blockIdx.y * 64;
    const int KH  = CIN / 2;
    const int cb0 = blockIdx.z * KH;
    float* __restrict__ Zp = blockIdx.z ? Zp1 : Zp0;

    float acc[4][4];
    #pragma unroll
    for (int i = 0; i < 4; ++i)
        #pragma unroll
        for (int j = 0; j < 4; ++j) acc[i][j] = 0.0f;

    const int sr = tid >> 6;         // A staging row base (0..3), rows sr+4i
    const int sc = tid & 63;         // A staging col
    const int wo = tid >> 5;         // W staging: o_local base (0..7)
    const int wl = tid & 31;         // W staging: c_local

    for (int cb = cb0; cb < cb0 + KH; cb += 32) {
        #pragma unroll
        for (int i = 0; i < 8; ++i)
            s_a[sr + 4 * i][sc] = A[(size_t)(cb + sr + 4 * i) * HW + px0 + sc];
        #pragma unroll
        for (int i = 0; i < 8; ++i)
            s_w[wl][wo + 8 * i] = Wm[(size_t)(o0 + wo + 8 * i) * CIN + cb + wl];
        __syncthreads();
        #pragma unroll
        for (int cc = 0; cc < 32; ++cc) {
            float4 a4 = *(const float4*)&s_a[cc][tx * 4];
            float4 w4 = *(const float4*)&s_w[cc][ty * 4];
            acc[0][0] += w4.x * a4.x; acc[0][1] += w4.x * a4.y;
            acc[0][2] += w4.x * a4.z; acc[0][3] += w4.x * a4.w;
            acc[1][0] += w4.y * a4.x; acc[1][1] += w4.y * a4.y;
            acc[1][2] += w4.y * a4.z; acc[1][3] += w4.y * a4.w;
            acc[2][0] += w4.z * a4.x; acc[2][1] += w4.z * a4.y;
            acc[2][2] += w4.z * a4.z; acc[2][3] += w4.z * a4.w;
            acc[3][0] += w4.w * a4.x; acc[3][1] += w4.w * a4.y;
            acc[3][2] += w4.w * a4.z; acc[3][3] += w4.w * a4.w;
        }
        __syncthreads();
    }

    #pragma unroll
    for (int i = 0; i < 4; ++i) {
        float4 v = make_float4(acc[i][0], acc[i][1], acc[i][2], acc[i][3]);
        *(float4*)&Zp[(size_t)(o0 + ty * 4 + i) * HW + px0 + tx * 4] = v;
    }
}

// ---------------------------------------------------------------------------
// Combine split-K partials + BN stats (float4):  Z = Zp0 + Zp1.
// grid = (128 ch x 4 segments).
// ---------------------------------------------------------------------------
__global__ __launch_bounds__(256) void k_combine(
    const float* __restrict__ Zp0,
    const float* __restrict__ Zp1,
    float* __restrict__ Z,
    float* __restrict__ psum)        // 128 x {sum,sumsq}, pre-zeroed
{
    __shared__ float s_s[4], s_q[4];
    const int c   = blockIdx.x >> 2;
    const int seg = blockIdx.x & 3;
    const int tid = threadIdx.x;
    const size_t base = (size_t)c * HW + seg * 3072;
    const float4* a4 = (const float4*)(Zp0 + base);
    const float4* b4 = (const float4*)(Zp1 + base);
    float4*       z4 = (float4*)(Z + base);
    float s = 0.0f, q = 0.0f;
    #pragma unroll
    for (int i = 0; i < 3; ++i) {
        float4 a = a4[tid + i * 256];
        float4 b = b4[tid + i * 256];
        float4 v = make_float4(a.x + b.x, a.y + b.y, a.z + b.z, a.w + b.w);
        z4[tid + i * 256] = v;
        s += v.x + v.y + v.z + v.w;
        q += v.x * v.x + v.y * v.y + v.z * v.z + v.w * v.w;
    }
    #pragma unroll
    for (int off = 32; off > 0; off >>= 1) {
        s += __shfl_down(s, off, 64);
        q += __shfl_down(q, off, 64);
    }
    if ((tid & 63) == 0) { s_s[tid >> 6] = s; s_q[tid >> 6] = q; }
    __syncthreads();
    if (tid == 0) {
        s = s_s[0] + s_s[1] + s_s[2] + s_s[3];
        q = s_q[0] + s_q[1] + s_q[2] + s_q[3];
        atomicAdd(&psum[2 * c],     s);
        atomicAdd(&psum[2 * c + 1], q);
    }
}

// ---------------------------------------------------------------------------
// Finalize BN params in place: (sum, sumsq) -> (scale, shift).  1 block.
// ---------------------------------------------------------------------------
__global__ void k_params(float* __restrict__ p,
                         const float* __restrict__ g,
                         const float* __restrict__ b)
{
    const int c = threadIdx.x;   // 128
    float s = p[2 * c], q = p[2 * c + 1];
    float mu  = s * (1.0f / HW);
    float var = q * (1.0f / HW) - mu * mu;
    float sc  = g[c] * rsqrtf(var + 1e-5f);
    p[2 * c]     = sc;
    p[2 * c + 1] = b[c] - mu * sc;
}

// ---------------------------------------------------------------------------
// Fused BN+LeakyReLU then depthwise 3x3 (zero pad 1).  4 px / thread:
// 18 loads -> 4 outputs, float4 store.  grid = 1536.
// ---------------------------------------------------------------------------
__global__ __launch_bounds__(256) void k_dw(
    const float* __restrict__ Z,
    const float* __restrict__ params,
    const float* __restrict__ dwgt,  // 128 x 9
    float4* __restrict__ D)
{
    const int t  = blockIdx.x * 256 + threadIdx.x;  // 0..393215
    const int c  = t / 3072;                        // HW/4 groups per channel
    const int g  = t - c * 3072;
    const int h  = g / 48;                          // 192/4 = 48 groups/row
    const int w0 = (g - h * 48) << 2;
    const float sc = params[2 * c];
    const float sh = params[2 * c + 1];
    float wk[9];
    #pragma unroll
    for (int k = 0; k < 9; ++k) wk[k] = dwgt[c * 9 + k];

    const float* zc = Z + (size_t)c * HW;
    float v[3][6];
    #pragma unroll
    for (int ky = 0; ky < 3; ++ky) {
        const int hh  = h + ky - 1;
        const bool rin = (hh >= 0) && (hh < Himg);
        #pragma unroll
        for (int j = 0; j < 6; ++j) {
            const int ww = w0 - 1 + j;
            const bool in = rin && (ww >= 0) && (ww < Wimg);
            float z = in ? zc[hh * Wimg + ww] : 0.0f;
            float y = z * sc + sh;
            y = (y >= 0.0f) ? y : 0.01f * y;
            v[ky][j] = in ? y : 0.0f;
        }
    }

    float o[4];
    #pragma unroll
    for (int j = 0; j < 4; ++j) {
        float a = 0.0f;
        #pragma unroll
        for (int ky = 0; ky < 3; ++ky)
            #pragma unroll
            for (int kx = 0; kx < 3; ++kx)
                a += wk[ky * 3 + kx] * v[ky][j + kx];
        o[j] = a;
    }
    D[t] = make_float4(o[0], o[1], o[2], o[3]);
}

// ---------------------------------------------------------------------------
// Final BN+LeakyReLU, float4.  grid = 1536.
// ---------------------------------------------------------------------------
__global__ __launch_bounds__(256) void k_final(
    const float4* __restrict__ Z,
    const float* __restrict__ params,
    float4* __restrict__ out)
{
    const int f = blockIdx.x * 256 + threadIdx.x;   // 0..393215
    const int c = f / 3072;                          // HW/4 = 3072
    const float sc = params[2 * c];
    const float sh = params[2 * c + 1];
    float4 z = Z[f];
    float4 v;
    v.x = z.x * sc + sh; v.x = (v.x >= 0.0f) ? v.x : 0.01f * v.x;
    v.y = z.y * sc + sh; v.y = (v.y >= 0.0f) ? v.y : 0.01f * v.y;
    v.z = z.z * sc + sh; v.z = (v.z >= 0.0f) ? v.z : 0.01f * v.z;
    v.w = z.w * sc + sh; v.w = (v.w >= 0.0f) ? v.w : 0.01f * v.w;
    out[f] = v;
}

// ---------------------------------------------------------------------------
extern "C" void kernel_launch(void* const* d_in, const int* in_sizes, int n_in,
                              void* d_out, int out_size, void* d_ws, size_t ws_size,
                              hipStream_t stream) {
    const float* x   = (const float*)d_in[0];
    const float* xr  = (const float*)d_in[1];
    const float* ro  = (const float*)d_in[2];
    const float* wr  = (const float*)d_in[3];
    const float* gr  = (const float*)d_in[4];
    const float* br  = (const float*)d_in[5];
    const float* dw1 = (const float*)d_in[6];
    const float* pw1 = (const float*)d_in[7];
    const float* g1  = (const float*)d_in[8];
    const float* b1  = (const float*)d_in[9];
    const float* dw2 = (const float*)d_in[10];
    const float* pw2 = (const float*)d_in[11];
    const float* g2  = (const float*)d_in[12];
    const float* b2  = (const float*)d_in[13];

    float* ws = (float*)d_ws;
    // A: 3,145,728 floats  (y0; later z|d pairs)
    // B: 1,572,864         (Zp0)
    // C: 1,572,864         (Zp1)
    float* A   = ws;
    float* B   = ws + 3145728;
    float* C   = ws + 4718592;
    float* y0  = A;
    float* zlo = A;                  // combined Z slots
    float* zhi = A + 1572864;        // d slots
    float* p1  = ws + 6291456;
    float* p2  = p1 + 256;
    float* p3  = p2 + 256;
    float* out = (float*)d_out;

    hipMemsetAsync(p1, 0, 768 * 4, stream);            // p1,p2,p3

    k_deform<<<dim3(8, 192), 256, 0, stream>>>(x, xr, ro, y0);
    k_pw<256><<<dim3(192, 2, 2), 256, 0, stream>>>(y0, wr, B, C);
    k_combine<<<512, 256, 0, stream>>>(B, C, zlo, p1); // y0 dead -> z1 = zlo
    k_params<<<1, 128, 0, stream>>>(p1, gr, br);
    k_dw<<<1536, 256, 0, stream>>>(zlo, p1, dw1, (float4*)zhi); // d1 = zhi
    k_pw<128><<<dim3(192, 2, 2), 256, 0, stream>>>(zhi, pw1, B, C);
    k_combine<<<512, 256, 0, stream>>>(B, C, zlo, p2); // z2 = zlo (z1 dead)
    k_params<<<1, 128, 0, stream>>>(p2, g1, b1);
    k_dw<<<1536, 256, 0, stream>>>(zlo, p2, dw2, (float4*)zhi); // d2 = zhi
    k_pw<128><<<dim3(192, 2, 2), 256, 0, stream>>>(zhi, pw2, B, C);
    k_combine<<<512, 256, 0, stream>>>(B, C, zlo, p3); // z3 = zlo
    k_params<<<1, 128, 0, stream>>>(p3, g2, b2);
    k_final<<<1536, 256, 0, stream>>>((const float4*)zlo, p3, (float4*)out);
}